// Round 14
// baseline (302.447 us; speedup 1.0000x reference)
//
#include <hip/hip_runtime.h>
#include <hip/hip_bf16.h>

typedef __attribute__((ext_vector_type(8))) short bf16x8;
typedef __attribute__((ext_vector_type(4))) float f32x4;
typedef __attribute__((ext_vector_type(16))) float f32x16;
typedef unsigned int uint;

typedef __attribute__((address_space(1))) void as1_void;
typedef __attribute__((address_space(3))) void as3_void;

__device__ __forceinline__ void gload16(const void* g, void* l) {
  __builtin_amdgcn_global_load_lds((as1_void*)(void*)g, (as3_void*)l, 16, 0, 0);
}

__device__ __forceinline__ f32x4 mfma16(bf16x8 a, bf16x8 b, f32x4 c) {
  return __builtin_amdgcn_mfma_f32_16x16x32_bf16(a, b, c, 0, 0, 0);
}

__device__ __forceinline__ f32x16 mfma32(bf16x8 a, bf16x8 b, f32x16 c) {
  return __builtin_amdgcn_mfma_f32_32x32x16_bf16(a, b, c, 0, 0, 0);
}

// ---------------- cast fp32 -> bf16, 4 elems/thread ----------------
__global__ __launch_bounds__(256) void castf2b(const float* __restrict__ s,
                                               __hip_bfloat16* __restrict__ d, int n) {
  int i = (blockIdx.x * 256 + threadIdx.x) * 4;
  if (i >= n) return;
  float4 f = *reinterpret_cast<const float4*>(s + i);
  union { __hip_bfloat16 h[4]; uint2 u; } cv;
  cv.h[0] = __float2bfloat16(f.x);
  cv.h[1] = __float2bfloat16(f.y);
  cv.h[2] = __float2bfloat16(f.z);
  cv.h[3] = __float2bfloat16(f.w);
  *reinterpret_cast<uint2*>(d + i) = cv.u;
}

// ---------------- cast all 4 weight matrices in one launch ----------------
__global__ __launch_bounds__(256) void castw(
    const float* __restrict__ Wq, const float* __restrict__ Wk,
    const float* __restrict__ Wv, const float* __restrict__ Wo,
    __hip_bfloat16* __restrict__ wqkv, __hip_bfloat16* __restrict__ wo) {
  int seg = blockIdx.x >> 10;
  int i = ((blockIdx.x & 1023) * 256 + threadIdx.x) * 4;
  const float* s = seg == 0 ? Wq : seg == 1 ? Wk : seg == 2 ? Wv : Wo;
  __hip_bfloat16* d = seg < 3 ? wqkv + seg * 1048576 : wo;
  float4 f = *reinterpret_cast<const float4*>(s + i);
  union { __hip_bfloat16 h[4]; uint2 u; } cv;
  cv.h[0] = __float2bfloat16(f.x);
  cv.h[1] = __float2bfloat16(f.y);
  cv.h[2] = __float2bfloat16(f.z);
  cv.h[3] = __float2bfloat16(f.w);
  *reinterpret_cast<uint2*>(d + i) = cv.u;
}

// ---------------- pack int32 mask -> bitmask (1 bit per element) ----------------
__global__ __launch_bounds__(256) void mask_pack(const int* __restrict__ m,
                                                 unsigned long long* __restrict__ bits) {
  int g = blockIdx.x * 256 + threadIdx.x;
  unsigned long long bal = __ballot(m[g] != 0);
  if ((threadIdx.x & 63) == 0) bits[g >> 6] = bal;
}

// ---------------- V transpose: [bh][2048][64] -> [bh][64][2048] ----------------
__global__ __launch_bounds__(256) void vtrans(const __hip_bfloat16* __restrict__ v,
                                              __hip_bfloat16* __restrict__ vt) {
  int bh = blockIdx.x >> 5;
  int s0 = (blockIdx.x & 31) * 64;
  __shared__ __align__(16) __hip_bfloat16 tile[64][72];
  const __hip_bfloat16* src = v + ((size_t)bh * 2048 + s0) * 64;
  int t = threadIdx.x;
#pragma unroll
  for (int i = 0; i < 2; i++) {
    int c = t + i * 256;
    int r = c >> 3, c8 = (c & 7) * 8;
    *reinterpret_cast<uint4*>(&tile[r][c8]) =
        *reinterpret_cast<const uint4*>(src + (size_t)r * 64 + c8);
  }
  __syncthreads();
  __hip_bfloat16* dst = vt + (size_t)bh * 64 * 2048 + s0;
#pragma unroll
  for (int i = 0; i < 2; i++) {
    int c = t + i * 256;
    int d = c >> 3, s8 = (c & 7) * 8;
    __hip_bfloat16 tmp[8] __attribute__((aligned(16)));
#pragma unroll
    for (int j = 0; j < 8; j++) tmp[j] = tile[s8 + j][d];
    *reinterpret_cast<uint4*>(dst + (size_t)d * 2048 + s8) =
        *reinterpret_cast<const uint4*>(tmp);
  }
}

// ---------------- QKV GEMM, 128x128x64 tile, 4 waves, XCD swizzle -----------
// A=x_bf16[4096,1024], B=Wqkv[3072,1024]; epilogue scatters q (x1/8), k, v
// into [bh][s][64] bf16 layouts with per-segment bias.
__global__ __launch_bounds__(256) void gemm_qkv(
    const __hip_bfloat16* __restrict__ A, const __hip_bfloat16* __restrict__ Bw,
    const float* __restrict__ bias0, const float* __restrict__ bias1,
    const float* __restrict__ bias2, __hip_bfloat16* __restrict__ out0,
    __hip_bfloat16* __restrict__ out1, __hip_bfloat16* __restrict__ out2,
    int M, int N, int K) {
  __shared__ __align__(16) __hip_bfloat16 Alds[128 * 64];
  __shared__ __align__(16) __hip_bfloat16 Blds[128 * 64];
  const int t = threadIdx.x;
  const int lane = t & 63;
  const int w = t >> 6;
  const int wr = w >> 1, wc = w & 1;
  const int l15 = lane & 15, lhi = lane >> 4;
  const int Nt = N >> 7;
  const int cpx = (int)gridDim.x >> 3;  // grid % 8 == 0
  const int bid = ((int)blockIdx.x & 7) * cpx + ((int)blockIdx.x >> 3);
  const int bm = bid / Nt, bn = bid % Nt;
  const int m0 = bm * 128, n0 = bn * 128;

  const f32x4 fzero = {0.f, 0.f, 0.f, 0.f};
  f32x4 acc[4][4];
#pragma unroll
  for (int mi = 0; mi < 4; mi++)
#pragma unroll
    for (int ni = 0; ni < 4; ni++) acc[mi][ni] = fzero;

  for (int k0 = 0; k0 < K; k0 += 64) {
#pragma unroll
    for (int i = 0; i < 4; i++) {
      int c = t + i * 256;           // 16B chunk id, 1024 per tile
      int r = c >> 3, c8 = (c & 7) * 8;
      gload16(A + (size_t)(m0 + r) * K + k0 + c8, (char*)Alds + c * 16);
      gload16(Bw + (size_t)(n0 + r) * K + k0 + c8, (char*)Blds + c * 16);
    }
    __syncthreads();
#pragma unroll
    for (int kk = 0; kk < 2; kk++) {
      bf16x8 af[4], bfr[4];
#pragma unroll
      for (int mi = 0; mi < 4; mi++)
        af[mi] = *reinterpret_cast<const bf16x8*>(
            &Alds[(wr * 64 + mi * 16 + l15) * 64 + kk * 32 + lhi * 8]);
#pragma unroll
      for (int ni = 0; ni < 4; ni++)
        bfr[ni] = *reinterpret_cast<const bf16x8*>(
            &Blds[(wc * 64 + ni * 16 + l15) * 64 + kk * 32 + lhi * 8]);
#pragma unroll
      for (int mi = 0; mi < 4; mi++)
#pragma unroll
        for (int ni = 0; ni < 4; ni++)
          acc[mi][ni] = mfma16(af[mi], bfr[ni], acc[mi][ni]);
    }
    __syncthreads();
  }

#pragma unroll
  for (int mi = 0; mi < 4; mi++) {
#pragma unroll
    for (int ni = 0; ni < 4; ni++) {
#pragma unroll
      for (int r = 0; r < 4; r++) {
        int gr = m0 + wr * 64 + mi * 16 + lhi * 4 + r;
        int gc = n0 + wc * 64 + ni * 16 + l15;
        float v = acc[mi][ni][r];
        int seg = gc >> 10, e = gc & 1023, h = e >> 6, d = e & 63;
        int b = gr >> 11, s = gr & 2047;
        size_t idx = (((size_t)(b * 16 + h)) * 2048 + s) * 64 + d;
        if (seg == 0)
          out0[idx] = __float2bfloat16((v + bias0[e]) * 0.125f);
        else if (seg == 1)
          out1[idx] = __float2bfloat16(v + bias1[e]);
        else
          out2[idx] = __float2bfloat16(v + bias2[e]);
      }
    }
  }
}

// ---------------- Output-proj GEMM, 64x128x64 tile, 4 waves (64x32 each) ----
// Round-13 lesson: 128x128 tile at M=4096,N=1024 gives 256 blocks = 1
// block/CU = 1 wave/SIMD -> all staging latency + barrier drains exposed.
// 64x128 tile -> 512 blocks = 2/CU restores cross-block overlap (m114).
__global__ __launch_bounds__(256) void gemm_out(
    const __hip_bfloat16* __restrict__ A, const __hip_bfloat16* __restrict__ Bw,
    const float* __restrict__ bias, float* __restrict__ out, int M, int N,
    int K) {
  __shared__ __align__(16) __hip_bfloat16 Alds[64 * 64];    // 8 KB
  __shared__ __align__(16) __hip_bfloat16 Blds[128 * 64];   // 16 KB
  const int t = threadIdx.x;
  const int lane = t & 63;
  const int w = t >> 6;
  const int l15 = lane & 15, lhi = lane >> 4;
  const int Nt = N >> 7;  // 8
  const int cpx = (int)gridDim.x >> 3;  // grid % 8 == 0
  const int bid = ((int)blockIdx.x & 7) * cpx + ((int)blockIdx.x >> 3);
  const int bm = bid / Nt, bn = bid % Nt;
  const int m0 = bm * 64, n0 = bn * 128;

  const f32x4 fzero = {0.f, 0.f, 0.f, 0.f};
  f32x4 acc[4][2];
#pragma unroll
  for (int mi = 0; mi < 4; mi++)
#pragma unroll
    for (int ni = 0; ni < 2; ni++) acc[mi][ni] = fzero;

  for (int k0 = 0; k0 < K; k0 += 64) {
#pragma unroll
    for (int i = 0; i < 2; i++) {  // A: 512 chunks
      int c = t + i * 256;
      int r = c >> 3, c8 = (c & 7) * 8;
      gload16(A + (size_t)(m0 + r) * K + k0 + c8, (char*)Alds + c * 16);
    }
#pragma unroll
    for (int i = 0; i < 4; i++) {  // B: 1024 chunks
      int c = t + i * 256;
      int r = c >> 3, c8 = (c & 7) * 8;
      gload16(Bw + (size_t)(n0 + r) * K + k0 + c8, (char*)Blds + c * 16);
    }
    __syncthreads();
#pragma unroll
    for (int kk = 0; kk < 2; kk++) {
      bf16x8 af[4], bfr[2];
#pragma unroll
      for (int mi = 0; mi < 4; mi++)
        af[mi] = *reinterpret_cast<const bf16x8*>(
            &Alds[(mi * 16 + l15) * 64 + kk * 32 + lhi * 8]);
#pragma unroll
      for (int ni = 0; ni < 2; ni++)
        bfr[ni] = *reinterpret_cast<const bf16x8*>(
            &Blds[(w * 32 + ni * 16 + l15) * 64 + kk * 32 + lhi * 8]);
#pragma unroll
      for (int mi = 0; mi < 4; mi++)
#pragma unroll
        for (int ni = 0; ni < 2; ni++)
          acc[mi][ni] = mfma16(af[mi], bfr[ni], acc[mi][ni]);
    }
    __syncthreads();
  }

#pragma unroll
  for (int mi = 0; mi < 4; mi++) {
#pragma unroll
    for (int ni = 0; ni < 2; ni++) {
#pragma unroll
      for (int r = 0; r < 4; r++) {
        int gr = m0 + mi * 16 + lhi * 4 + r;
        int gc = n0 + w * 32 + ni * 16 + l15;
        out[(size_t)gr * N + gc] = acc[mi][ni][r] + bias[gc];
      }
    }
  }
}

// ---------------- Flash attention v4: LDS-staged KV, transposed-chunk layout -
// (unchanged from round 13 — verified: 93 us, conflicts 0, absmax 4.88e-4)
__global__ __launch_bounds__(256, 4) void attn3(
    const __hip_bfloat16* __restrict__ Q, const __hip_bfloat16* __restrict__ Kk,
    const __hip_bfloat16* __restrict__ VT,
    const unsigned long long* __restrict__ mb, __hip_bfloat16* __restrict__ ctx) {
  int bx = blockIdx.x;
  int bid = (bx & 7) * 128 + (bx >> 3);  // XCD swizzle, bijective (1024 = 8*128)
  int bh = bid >> 5, qc = bid & 31;
  int b = bh >> 4, h = bh & 15;
  int lane = threadIdx.x & 63, w = threadIdx.x >> 6;
  int l31 = lane & 31, lh = lane >> 5, lh4 = lh * 4;
  int wsb = w & 1;        // q-sub within block
  int kvh = w >> 1;       // kv half
  int q0 = qc * 64 + wsb * 32;

  // [buf][section: K half0, K half1, V half0, V half1][4KB]
  __shared__ __align__(16) char tiles[2][4][4096];
  __shared__ float mlds[2][2][32];
  __shared__ float llds[2][2][32];
  float* olds = (float*)&tiles[0][0][0];  // merge scratch overlays tiles (16KB)

  const int t = threadIdx.x;
  const __hip_bfloat16* Kg = Kk + (size_t)bh * 2048 * 64;
  const __hip_bfloat16* Vg = VT + (size_t)bh * 64 * 2048;
  const unsigned long long* Mrow =
      mb + ((size_t)b * 2048 + q0 + l31) * 32 + kvh * 16;

  bf16x8 qf[4];
  {
    const __hip_bfloat16* Qrow =
        Q + ((size_t)bh * 2048 + q0 + l31) * 64 + lh * 8;
#pragma unroll
    for (int ck = 0; ck < 4; ck++)
      qf[ck] = *reinterpret_cast<const bf16x8*>(Qrow + ck * 16);
  }

  auto stage = [&](int buf, int kvt) {
    {
      int r = t & 31, s = t >> 5;
      gload16(Kg + (size_t)(kvt * 32 + r) * 64 + s * 8,
              &tiles[buf][0][t * 16]);
      gload16(Kg + (size_t)(1024 + kvt * 32 + r) * 64 + s * 8,
              &tiles[buf][1][t * 16]);
    }
    {
      int r = t & 63, s = t >> 6;
      gload16(Vg + (size_t)r * 2048 + kvt * 32 + s * 8,
              &tiles[buf][2][t * 16]);
      gload16(Vg + (size_t)r * 2048 + 1024 + kvt * 32 + s * 8,
              &tiles[buf][3][t * 16]);
    }
  };

  f32x16 o0 = {}, o1 = {};
  float mrun = -3.0e38f, lrun = 0.f;

  stage(0, 0);
  __syncthreads();

  unsigned long long mw = ~0ull;
  bool skipm = true;

  for (int i = 0; i < 32; ++i) {
    const int cur = i & 1;
    if (i < 31) stage(cur ^ 1, i + 1);
    if ((i & 1) == 0) {
      mw = Mrow[i >> 1];
      skipm = __all(mw == ~0ull);
    }
    const int sh = (i & 1) * 32;

    const bf16x8* kb = (const bf16x8*)&tiles[cur][kvh][0];
    const bf16x8* vb = (const bf16x8*)&tiles[cur][2 + kvh][0];

    f32x16 s = {};
    {
      bf16x8 kf[4];
#pragma unroll
      for (int ck = 0; ck < 4; ck++) kf[ck] = kb[(ck * 2 + lh) * 32 + l31];
#pragma unroll
      for (int ck = 0; ck < 4; ck++) s = mfma32(kf[ck], qf[ck], s);
    }
    bf16x8 vf[4];
#pragma unroll
    for (int j = 0; j < 4; j++)
      vf[j] = vb[((j & 1) * 2 + lh) * 64 + (j >> 1) * 32 + l31];

    if (!skipm) {
      uint mh = (uint)(mw >> sh) >> lh4;
#pragma unroll
      for (int r = 0; r < 16; r++) {
        int cr = (r & 3) + 8 * (r >> 2);
        if (!((mh >> cr) & 1u)) s[r] = -1e9f;
      }
    }
    float pmax = s[0];
#pragma unroll
    for (int r = 1; r < 16; r++) pmax = fmaxf(pmax, s[r]);
    pmax = fmaxf(pmax, __shfl_xor(pmax, 32));  // cross-half max
    if (!__all(pmax <= mrun + 8.0f)) {  // defer-max (T13), wave-uniform
      float nm = fmaxf(mrun, pmax);
      float scl = __expf(mrun - nm);
      mrun = nm;
      lrun *= scl;
#pragma unroll
      for (int r = 0; r < 16; r++) {
        int cr = (r & 3) + 8 * (r >> 2);
        float sr = __shfl(scl, cr + lh4);
        o0[r] *= sr;
        o1[r] *= sr;
      }
    }
    float p[16];
    float ts = 0.f;
#pragma unroll
    for (int r = 0; r < 16; r++) {
      p[r] = __expf(s[r] - mrun);
      ts += p[r];
    }
    ts += __shfl_xor(ts, 32);  // cross-half sum
    lrun += ts;
    uint x0, x1, x2, x3, y0, y1, y2, y3;
    asm("v_cvt_pk_bf16_f32 %0, %1, %2" : "=v"(x0) : "v"(p[0]), "v"(p[1]));
    asm("v_cvt_pk_bf16_f32 %0, %1, %2" : "=v"(y0) : "v"(p[4]), "v"(p[5]));
    asm("v_cvt_pk_bf16_f32 %0, %1, %2" : "=v"(x1) : "v"(p[2]), "v"(p[3]));
    asm("v_cvt_pk_bf16_f32 %0, %1, %2" : "=v"(y1) : "v"(p[6]), "v"(p[7]));
    asm("v_cvt_pk_bf16_f32 %0, %1, %2" : "=v"(x2) : "v"(p[8]), "v"(p[9]));
    asm("v_cvt_pk_bf16_f32 %0, %1, %2" : "=v"(y2) : "v"(p[12]), "v"(p[13]));
    asm("v_cvt_pk_bf16_f32 %0, %1, %2" : "=v"(x3) : "v"(p[10]), "v"(p[11]));
    asm("v_cvt_pk_bf16_f32 %0, %1, %2" : "=v"(y3) : "v"(p[14]), "v"(p[15]));
    asm volatile("v_permlane32_swap_b32 %0, %1" : "+v"(x0), "+v"(y0));
    asm volatile("v_permlane32_swap_b32 %0, %1" : "+v"(x1), "+v"(y1));
    asm volatile("v_permlane32_swap_b32 %0, %1" : "+v"(x2), "+v"(y2));
    asm volatile("v_permlane32_swap_b32 %0, %1" : "+v"(x3), "+v"(y3));
    union { uint u[4]; bf16x8 v8; } pa0, pa1;
    pa0.u[0] = x0; pa0.u[1] = x1; pa0.u[2] = y0; pa0.u[3] = y1;
    pa1.u[0] = x2; pa1.u[1] = x3; pa1.u[2] = y2; pa1.u[3] = y3;
    o0 = mfma32(pa0.v8, vf[0], o0);
    o0 = mfma32(pa1.v8, vf[1], o0);
    o1 = mfma32(pa0.v8, vf[2], o1);
    o1 = mfma32(pa1.v8, vf[3], o1);

    __syncthreads();  // reads of buf cur done; staged tile i+1 landed
  }

  // ---- merge kv-halves (waves w and w+2 share q-sub wsb) ----
  if (lh == 0) {
    mlds[wsb][kvh][l31] = mrun;
    llds[wsb][kvh][l31] = lrun;
  }
  __syncthreads();
  float mA = mlds[wsb][0][l31], mB = mlds[wsb][1][l31];
  float lA = llds[wsb][0][l31], lB = llds[wsb][1][l31];
  float mN = fmaxf(mA, mB);
  float aA = __expf(mA - mN), aB = __expf(mB - mN);
  if (kvh) {  // high wave: scale own o, deposit to LDS (layout [reg][lane])
#pragma unroll
    for (int r = 0; r < 16; r++) {
      int cr = (r & 3) + 8 * (r >> 2);
      float ar = __shfl(aB, cr + lh4);
      olds[(wsb * 32 + r) * 64 + lane] = o0[r] * ar;
      olds[(wsb * 32 + 16 + r) * 64 + lane] = o1[r] * ar;
    }
  }
  __syncthreads();
  if (!kvh) {  // low wave: merge + epilogue
    float linv = 1.0f / (lA * aA + lB * aB);
    size_t obase = ((size_t)b * 2048 + q0) * 1024 + (size_t)h * 64 + l31;
#pragma unroll
    for (int r = 0; r < 16; r++) {
      int cr = (r & 3) + 8 * (r >> 2);
      int rho = cr + lh4;
      float ar = __shfl(aA, rho);
      float li = __shfl(linv, rho);
      float v0 = o0[r] * ar + olds[(wsb * 32 + r) * 64 + lane];
      float v1 = o1[r] * ar + olds[(wsb * 32 + 16 + r) * 64 + lane];
      ctx[obase + (size_t)rho * 1024] = __float2bfloat16(v0 * li);
      ctx[obase + (size_t)rho * 1024 + 32] = __float2bfloat16(v1 * li);
    }
  }
}

extern "C" void kernel_launch(void* const* d_in, const int* in_sizes, int n_in,
                              void* d_out, int out_size, void* d_ws,
                              size_t ws_size, hipStream_t stream) {
  const float* x = (const float*)d_in[0];
  const int* mask = (const int*)d_in[1];
  const float* Wq = (const float*)d_in[2];
  const float* bq = (const float*)d_in[3];
  const float* Wk = (const float*)d_in[4];
  const float* bk = (const float*)d_in[5];
  const float* Wv = (const float*)d_in[6];
  const float* bv = (const float*)d_in[7];
  const float* Wo = (const float*)d_in[8];
  const float* bo = (const float*)d_in[9];
  float* out = (float*)d_out;  // reference output dtype is float32
  char* ws = (char*)d_ws;

  // ws layout (bytes)
  __hip_bfloat16* xb   = (__hip_bfloat16*)(ws);              // 8 MiB
  __hip_bfloat16* wqkv = (__hip_bfloat16*)(ws + 8388608);    // 6 MiB
  __hip_bfloat16* wo   = (__hip_bfloat16*)(ws + 14680064);   // 2 MiB
  __hip_bfloat16* qws  = (__hip_bfloat16*)(ws + 16777216);   // 8 MiB
  __hip_bfloat16* kws  = (__hip_bfloat16*)(ws + 25165824);   // 8 MiB
  __hip_bfloat16* vtmp = (__hip_bfloat16*)(ws + 33554432);   // 8 MiB
  __hip_bfloat16* vt   = (__hip_bfloat16*)(ws + 41943040);   // 8 MiB
  __hip_bfloat16* ctx  = (__hip_bfloat16*)(ws + 50331648);   // 8 MiB
  unsigned long long* mbits = (unsigned long long*)(ws + 58720256);  // 1 MiB

  castf2b<<<4096, 256, 0, stream>>>(x, xb, 4194304);
  castw<<<4096, 256, 0, stream>>>(Wq, Wk, Wv, Wo, wqkv, wo);
  mask_pack<<<32768, 256, 0, stream>>>(mask, mbits);

  gemm_qkv<<<768, 256, 0, stream>>>(xb, wqkv, bq, bk, bv, qws, kws, vtmp,
                                    4096, 3072, 1024);
  vtrans<<<1024, 256, 0, stream>>>(vtmp, vt);
  attn3<<<1024, 256, 0, stream>>>(qws, kws, vt, mbits, ctx);
  gemm_out<<<512, 256, 0, stream>>>(ctx, wo, bo, out, 4096, 1024, 1024);
}